// Round 15
// baseline (202.831 us; speedup 1.0000x reference)
//
#include <hip/hip_runtime.h>
#include <hip/hip_bf16.h>

#define BB   256
#define II   1152
#define OO   10
#define DOUT 16
#define NIC  96   // i-chunks (12 i each)
#define CI   12
#define PCHH 24   // f16 stride per (o,dsub) chunk: 12 dwords -> dsub*12 mod 32 disjoint bank-quads

using h2 = __fp16 __attribute__((ext_vector_type(2)));
using h8 = __fp16 __attribute__((ext_vector_type(8)));
#define H2V(v, a, b) __builtin_shufflevector((v), (v), (a), (b))
#define FD(a, b, c)  __builtin_amdgcn_fdot2((a), (b), (c), false)   // v_dot2_f32_f16: f32 accumulate

// Cross-lane reduce: xor1/xor2 on the VALU pipe (DPP quad_perm), xor4 on DS.
__device__ __forceinline__ float dpp_add_xor1(float v) {
  int r = __builtin_amdgcn_mov_dpp(__float_as_int(v), 0xB1, 0xF, 0xF, true);
  return v + __int_as_float(r);
}
__device__ __forceinline__ float dpp_add_xor2(float v) {
  int r = __builtin_amdgcn_mov_dpp(__float_as_int(v), 0x4E, 0xF, 0xF, true);
  return v + __int_as_float(r);
}
__device__ __forceinline__ float swz_add_xor4(float v) {
  int r = __builtin_amdgcn_ds_swizzle(__float_as_int(v), 0x101F);
  return v + __int_as_float(r);
}

// Pass kernel K: rebuilds V = sum_{j<K} squash(plane_j) locally per block
// (kernel-boundary coherence covers the cross-XCD atomic writes of the
// previous pass -- same guarantee R6-R13's reduce kernels used), then runs
// the R13-validated body (f16 LDS tiles, dot2, DPP reduce, atomic plane
// accumulate). Eliminates the 2 intermediate reduce dispatches (R13 wall
// 185 vs 153 dispatch-sum: ~32 us launch overhead). Grid 1536 = 96 ic x
// 16 bg: LDS 26.1 KB x 6 = 156.7 <= 160 KB, VGPR ~64 -> 6 blocks/CU =
// 24 waves/CU (R13 had 16) to fill barrier-phasing gaps.
template<int K>
__global__ __launch_bounds__(256, 3) void pass_kernel(
    const float* __restrict__ x,      // fp32 [B][I][8]
    const float* __restrict__ w,      // fp32 [O][I][16][8]
    float* __restrict__ planes)       // fp32 [3][B][O][16] (pre-zeroed)
{
  const int tid  = threadIdx.x;
  const int lane = tid & 63;
  const int wv   = tid >> 6;
  const int bh   = wv & 1;               // b-half of the block's 16 batches
  const int ih   = wv >> 1;              // i-half (6 i each)
  const int dsub = lane & 7;             // d-pair index
  const int bl   = lane >> 3;            // batch-in-wave (8)
  const int ic   = blockIdx.x % NIC;     // fast-varying: ic%8 = XCD -> local w
  const int bg   = blockIdx.x / NIC;     // 16 batches per block
  const int b    = bg * 16 + bh * 8 + bl;
  const int i0   = ic * CI + ih * 6;
  const size_t P = (size_t)BB * OO * DOUT;

  __shared__ __fp16 wt[2][2][OO * 8 * PCHH];   // f16 tiles, 15.4 KB
  __shared__ float red[16][168];               // V staging / cross-ih reduce

  // --- rebuild V for this block's 16 batches (K>=1) ---
  float Vr[OO][2];
  if (K >= 1) {
    if (tid < 160) {
      const int bl16 = tid & 15, o = tid >> 4;
      const size_t base = (((size_t)bg * 16 + bl16) * OO + o) * DOUT;
      float acc[DOUT];
#pragma unroll
      for (int d = 0; d < DOUT; ++d) acc[d] = 0.f;
#pragma unroll 1
      for (int j = 0; j < K; ++j) {
        float sv[DOUT];
        float sq = 0.f;
#pragma unroll
        for (int d = 0; d < DOUT; ++d) {
          sv[d] = planes[(size_t)j * P + base + d];
          sq += sv[d] * sv[d];
        }
        const float mag = sqrtf(sq);
        const float f = sq / (1.f + sq) / (mag + 1e-8f);
#pragma unroll
        for (int d = 0; d < DOUT; ++d) acc[d] += f * sv[d];
      }
#pragma unroll
      for (int d = 0; d < DOUT; ++d) red[bl16][o * 16 + d] = acc[d];
    }
    __syncthreads();
#pragma unroll
    for (int o = 0; o < OO; ++o) {
      Vr[o][0] = red[bh * 8 + bl][o * 16 + dsub * 2];
      Vr[o][1] = red[bh * 8 + bl][o * 16 + dsub * 2 + 1];
    }
    // no extra barrier needed: 6 in-loop barriers pass before red is rewritten
  }

  float s[OO][2];
#pragma unroll
  for (int o = 0; o < OO; ++o) { s[o][0] = 0.f; s[o][1] = 0.f; }

  // staging: 128 lanes (this i-half's wave pair) load w row i as float2 -> f16
  const int p    = bh * 64 + lane;       // 0..127
  const int so   = p >> 6;               // o parity (== bh)
  const int idx2 = (p & 63) * 2;         // even element within o-row
  const int sds  = idx2 >> 4;            // dsub 0..7
  const int ssk  = idx2 & 15;            // 0,2,..,14

  #define STAGE(i, buf)                                                        \
    {                                                                          \
      _Pragma("unroll")                                                        \
      for (int og = 0; og < 5; ++og) {                                         \
        const int o = og * 2 + so;                                             \
        const float2 v2 = *(const float2*)(w + ((size_t)o * II + (i)) * 128 + idx2); \
        *(h2*)&wt[ih][buf][(o * 8 + sds) * PCHH + ssk] =                       \
            __builtin_amdgcn_cvt_pkrtz(v2.x, v2.y);                            \
      }                                                                        \
    }

  STAGE(i0, 0)
#pragma unroll 1
  for (int ii = 0; ii < 6; ++ii) {
    __syncthreads();                    // wt[ih][ii&1] ready; prev reads done
    const int cur = ii & 1;
    if (ii < 5) STAGE(i0 + ii + 1, cur ^ 1)

    const int i = i0 + ii;
    const float* xp = x + ((size_t)b * II + i) * 8;
    const float4 x0 = *(const float4*)(xp);
    const float4 x1 = *(const float4*)(xp + 4);
    const h2 xq0 = __builtin_amdgcn_cvt_pkrtz(x0.x, x0.y);
    const h2 xq1 = __builtin_amdgcn_cvt_pkrtz(x0.z, x0.w);
    const h2 xq2 = __builtin_amdgcn_cvt_pkrtz(x1.x, x1.y);
    const h2 xq3 = __builtin_amdgcn_cvt_pkrtz(x1.z, x1.w);

    float xh[OO][2];
    float t[OO];
    const __fp16* wtb = wt[ih][cur];
#pragma unroll 2
    for (int o = 0; o < OO; ++o) {
      const __fp16* cp = wtb + (o * 8 + dsub) * PCHH;
      const h8 wa = *(const h8*)(cp);
      const h8 wb = *(const h8*)(cp + 8);
      xh[o][0] = FD(H2V(wa, 0, 1), xq0, FD(H2V(wa, 2, 3), xq1,
                 FD(H2V(wa, 4, 5), xq2, FD(H2V(wa, 6, 7), xq3, 0.f))));
      xh[o][1] = FD(H2V(wb, 0, 1), xq0, FD(H2V(wb, 2, 3), xq1,
                 FD(H2V(wb, 4, 5), xq2, FD(H2V(wb, 6, 7), xq3, 0.f))));
      if (K >= 1)
        t[o] = Vr[o][0] * xh[o][0] + Vr[o][1] * xh[o][1];
    }

    if (K == 0) {
#pragma unroll
      for (int o = 0; o < OO; ++o) { s[o][0] += xh[o][0]; s[o][1] += xh[o][1]; }
    } else {
#pragma unroll
      for (int o = 0; o < OO; ++o) {     // reduce over the 8 dsub lanes
        t[o] = dpp_add_xor1(t[o]);       // VALU pipe
        t[o] = dpp_add_xor2(t[o]);       // VALU pipe
        t[o] = swz_add_xor4(t[o]);       // DS pipe
      }
      float sum = 0.f;
#pragma unroll
      for (int o = 0; o < OO; ++o) { t[o] = __expf(t[o]); sum += t[o]; }
      const float inv = __builtin_amdgcn_rcpf(sum);  // |t|<1 pre-exp; 1-ulp ok
#pragma unroll
      for (int o = 0; o < OO; ++o) {
        const float c = t[o] * inv;
        s[o][0] += c * xh[o][0];
        s[o][1] += c * xh[o][1];
      }
    }
  }

  if (K == 0) {
#pragma unroll
    for (int o = 0; o < OO; ++o) { s[o][0] *= 0.1f; s[o][1] *= 0.1f; }
  }

  // cross-i-half reduce: ih=1 parks s in LDS; ih=0 adds and atomically
  // accumulates into plane_K.
  if (ih == 1) {
#pragma unroll
    for (int o = 0; o < OO; ++o) {
      red[bh * 8 + bl][o * 16 + dsub * 2]     = s[o][0];
      red[bh * 8 + bl][o * 16 + dsub * 2 + 1] = s[o][1];
    }
  }
  __syncthreads();
  if (ih == 0) {
    float* op = planes + (size_t)K * P + (size_t)b * (OO * DOUT);
    const float* rr = red[bh * 8 + bl];
#pragma unroll
    for (int o = 0; o < OO; ++o) {
      unsafeAtomicAdd(&op[o * 16 + dsub * 2],     s[o][0] + rr[o * 16 + dsub * 2]);
      unsafeAtomicAdd(&op[o * 16 + dsub * 2 + 1], s[o][1] + rr[o * 16 + dsub * 2 + 1]);
    }
  }
}

// Final squash: plane_2 -> output.
__global__ __launch_bounds__(256) void final_kernel(
    const float* __restrict__ plane,   // [B*O*DOUT] (plane 2)
    float* __restrict__ out)           // fp32 [B*O*DOUT]
{
  const int idx = blockIdx.x * 256 + threadIdx.x;    // over B*O*DOUT = 40960
  const float s = plane[idx];

  float sq = s * s;
  sq += __shfl_xor(sq, 1);
  sq += __shfl_xor(sq, 2);
  sq += __shfl_xor(sq, 4);
  sq += __shfl_xor(sq, 8);
  const float mag = sqrtf(sq);
  out[idx] = sq / (1.f + sq) * (s / (mag + 1e-8f));
}

extern "C" void kernel_launch(void* const* d_in, const int* in_sizes, int n_in,
                              void* d_out, int out_size, void* d_ws, size_t ws_size,
                              hipStream_t stream) {
  const float* x = (const float*)d_in[0];   // fp32 [256,1152,8]
  const float* w = (const float*)d_in[1];   // fp32 [10,1152,16,8]
  float* out = (float*)d_out;               // fp32 [256,10,16]
  float* planes = (float*)d_ws;             // 3 planes of B*O*DOUT floats

  const size_t P = (size_t)BB * OO * DOUT;
  hipMemsetAsync(planes, 0, 3 * P * sizeof(float), stream);

  const int pg = NIC * 16;                  // 1536 blocks: 6/CU, 24 waves/CU
  pass_kernel<0><<<pg, 256, 0, stream>>>(x, w, planes);
  pass_kernel<1><<<pg, 256, 0, stream>>>(x, w, planes);
  pass_kernel<2><<<pg, 256, 0, stream>>>(x, w, planes);
  final_kernel<<<(int)(P / 256), 256, 0, stream>>>(planes + 2 * P, out);
}

// Round 16
// 196.506 us; speedup vs baseline: 1.0322x; 1.0322x over previous
//
#include <hip/hip_runtime.h>
#include <hip/hip_bf16.h>

#define BB   256
#define II   1152
#define OO   10
#define DOUT 16
#define PCHH 24   // f16 stride per (o,dsub) chunk: 12 dwords -> dsub*12 mod 32 disjoint bank-quads

using h2 = __fp16 __attribute__((ext_vector_type(2)));
using h8 = __fp16 __attribute__((ext_vector_type(8)));
#define H2V(v, a, b) __builtin_shufflevector((v), (v), (a), (b))
#define FD(a, b, c)  __builtin_amdgcn_fdot2((a), (b), (c), false)   // v_dot2_f32_f16: f32 accumulate

// Cross-lane reduce: xor1/xor2 on the VALU pipe (DPP quad_perm), xor4 on DS.
__device__ __forceinline__ float dpp_add_xor1(float v) {
  int r = __builtin_amdgcn_mov_dpp(__float_as_int(v), 0xB1, 0xF, 0xF, true);
  return v + __int_as_float(r);
}
__device__ __forceinline__ float dpp_add_xor2(float v) {
  int r = __builtin_amdgcn_mov_dpp(__float_as_int(v), 0x4E, 0xF, 0xF, true);
  return v + __int_as_float(r);
}
__device__ __forceinline__ float swz_add_xor4(float v) {
  int r = __builtin_amdgcn_ds_swizzle(__float_as_int(v), 0x101F);
  return v + __int_as_float(r);
}

// R13 pass kernel + 2-row barrier phases: stage TWO w-rows per __syncthreads
// (wt[ih][buf][2 rows]) -> in-loop barriers 9 -> 5. R13's measured gap above
// the DS+VALU floor (~48 vs ~30 us) is barrier-phasing loss across 10 sync
// points; halving them is the one contained lever left (R15's fusion and
// wider grids both regressed). Everything else byte-identical to R13:
// f16 LDS tiles + dot2 (f32 acc), DPP xor1/2 + ds_swizzle xor4, single
// atomic plane per pass, separate reduce kernels, 64 ic x 16 bg, (256,3).
template<int K>
__global__ __launch_bounds__(256, 3) void pass_kernel(
    const float* __restrict__ x,     // fp32 [B][I][8]
    const float* __restrict__ w,     // fp32 [O][I][16][8]
    const float* __restrict__ V,     // fp32 [B][O][16]
    float* __restrict__ plane)       // fp32 [B][O][16] accumulator (pre-zeroed)
{
  const int tid  = threadIdx.x;
  const int lane = tid & 63;
  const int wv   = tid >> 6;
  const int bh   = wv & 1;             // b-half of the block's 16 batches
  const int ih   = wv >> 1;            // i-half (9 i each)
  const int dsub = lane & 7;           // d-pair index (d = 2*dsub + dlo)
  const int bl   = lane >> 3;          // batch-in-wave (8)
  const int ic   = blockIdx.x & 63;    // i-chunk (18 i), fast => XCD-local w
  const int bg   = blockIdx.x >> 6;    // 16 batches per block
  const int b    = bg * 16 + bh * 8 + bl;
  const int i0   = ic * 18 + ih * 9;

  __shared__ __fp16 wt[2][2][2][OO * 8 * PCHH];  // [ih][buf][row]: 30.7 KB
  __shared__ float red[16][168];                 // cross-ih reduce, padded rows

  float Vr[OO][2];
  if (K >= 1) {
#pragma unroll
    for (int o = 0; o < OO; ++o) {
      const float2 v2 = *(const float2*)(V + (b * OO + o) * DOUT + dsub * 2);
      Vr[o][0] = v2.x; Vr[o][1] = v2.y;
    }
  }

  float s[OO][2];
#pragma unroll
  for (int o = 0; o < OO; ++o) { s[o][0] = 0.f; s[o][1] = 0.f; }

  // staging: 128 lanes load w row i (1280 floats) as float2, convert to f16.
  const int p    = bh * 64 + lane;       // 0..127
  const int so   = p >> 6;               // o parity (== bh)
  const int idx2 = (p & 63) * 2;         // even element within o-row
  const int sds  = idx2 >> 4;            // dsub 0..7
  const int ssk  = idx2 & 15;            // 0,2,..,14

  #define STAGE(i, buf, slot)                                                  \
    {                                                                          \
      _Pragma("unroll")                                                        \
      for (int og = 0; og < 5; ++og) {                                         \
        const int o = og * 2 + so;                                             \
        const float2 v2 = *(const float2*)(w + ((size_t)o * II + (i)) * 128 + idx2); \
        *(h2*)&wt[ih][buf][slot][(o * 8 + sds) * PCHH + ssk] =                 \
            __builtin_amdgcn_cvt_pkrtz(v2.x, v2.y);                            \
      }                                                                        \
    }

  STAGE(i0, 0, 0)
  STAGE(i0 + 1, 0, 1)
#pragma unroll 1
  for (int ph = 0; ph < 5; ++ph) {       // phases: rows {0,1}{2,3}{4,5}{6,7}{8}
    __syncthreads();                     // wt[ih][ph&1] ready; prev reads done
    const int cur = ph & 1;
    if (ph < 4) {
      const int ni = i0 + (ph + 1) * 2;
      STAGE(ni, cur ^ 1, 0)
      if (ph < 3) STAGE(ni + 1, cur ^ 1, 1)
    }

    const int nrow = (ph < 4) ? 2 : 1;
#pragma unroll 1
    for (int r = 0; r < nrow; ++r) {
      const int i = i0 + ph * 2 + r;
      const float* xp = x + ((size_t)b * II + i) * 8;
      const float4 x0 = *(const float4*)(xp);
      const float4 x1 = *(const float4*)(xp + 4);
      const h2 xq0 = __builtin_amdgcn_cvt_pkrtz(x0.x, x0.y);
      const h2 xq1 = __builtin_amdgcn_cvt_pkrtz(x0.z, x0.w);
      const h2 xq2 = __builtin_amdgcn_cvt_pkrtz(x1.x, x1.y);
      const h2 xq3 = __builtin_amdgcn_cvt_pkrtz(x1.z, x1.w);

      float xh[OO][2];
      float t[OO];
      const __fp16* wtb = wt[ih][cur][r];
#pragma unroll 2
      for (int o = 0; o < OO; ++o) {
        const __fp16* cp = wtb + (o * 8 + dsub) * PCHH;
        const h8 wa = *(const h8*)(cp);
        const h8 wb = *(const h8*)(cp + 8);
        xh[o][0] = FD(H2V(wa, 0, 1), xq0, FD(H2V(wa, 2, 3), xq1,
                   FD(H2V(wa, 4, 5), xq2, FD(H2V(wa, 6, 7), xq3, 0.f))));
        xh[o][1] = FD(H2V(wb, 0, 1), xq0, FD(H2V(wb, 2, 3), xq1,
                   FD(H2V(wb, 4, 5), xq2, FD(H2V(wb, 6, 7), xq3, 0.f))));
        if (K >= 1)
          t[o] = Vr[o][0] * xh[o][0] + Vr[o][1] * xh[o][1];
      }

      if (K == 0) {
#pragma unroll
        for (int o = 0; o < OO; ++o) { s[o][0] += xh[o][0]; s[o][1] += xh[o][1]; }
      } else {
#pragma unroll
        for (int o = 0; o < OO; ++o) {   // reduce over the 8 dsub lanes
          t[o] = dpp_add_xor1(t[o]);     // VALU pipe
          t[o] = dpp_add_xor2(t[o]);     // VALU pipe
          t[o] = swz_add_xor4(t[o]);     // DS pipe (10/row)
        }
        float sum = 0.f;
#pragma unroll
        for (int o = 0; o < OO; ++o) { t[o] = __expf(t[o]); sum += t[o]; }
        const float inv = __builtin_amdgcn_rcpf(sum);  // |t|<1 pre-exp; 1-ulp ok
#pragma unroll
        for (int o = 0; o < OO; ++o) {
          const float c = t[o] * inv;
          s[o][0] += c * xh[o][0];
          s[o][1] += c * xh[o][1];
        }
      }
    }
  }

  if (K == 0) {
#pragma unroll
    for (int o = 0; o < OO; ++o) { s[o][0] *= 0.1f; s[o][1] *= 0.1f; }
  }

  // cross-i-half reduce: ih=1 parks s in LDS; ih=0 adds and atomically
  // accumulates into the single global plane.
  if (ih == 1) {
#pragma unroll
    for (int o = 0; o < OO; ++o) {
      red[bh * 8 + bl][o * 16 + dsub * 2]     = s[o][0];
      red[bh * 8 + bl][o * 16 + dsub * 2 + 1] = s[o][1];
    }
  }
  __syncthreads();
  if (ih == 0) {
    float* op = plane + (size_t)b * (OO * DOUT);
    const float* rr = red[bh * 8 + bl];
#pragma unroll
    for (int o = 0; o < OO; ++o) {
      unsafeAtomicAdd(&op[o * 16 + dsub * 2],     s[o][0] + rr[o * 16 + dsub * 2]);
      unsafeAtomicAdd(&op[o * 16 + dsub * 2 + 1], s[o][1] + rr[o * 16 + dsub * 2 + 1]);
    }
  }
}

// Squash the accumulated plane, update V / write final output.
template<int K>
__global__ __launch_bounds__(256) void reduce_kernel(
    const float* __restrict__ plane,   // [B*O*DOUT]
    float* __restrict__ V,             // [B*O*DOUT]
    float* __restrict__ out)           // fp32 [B*O*DOUT]
{
  const int idx = blockIdx.x * 256 + threadIdx.x;    // over B*O*DOUT = 40960
  const float s = plane[idx];

  // squash over the 16 Dout lanes (contiguous 16-lane groups share (b,o))
  float sq = s * s;
  sq += __shfl_xor(sq, 1);
  sq += __shfl_xor(sq, 2);
  sq += __shfl_xor(sq, 4);
  sq += __shfl_xor(sq, 8);
  const float mag = sqrtf(sq);
  const float v = sq / (1.f + sq) * (s / (mag + 1e-8f));

  if (K == 0)      V[idx] = v;
  else if (K == 1) V[idx] += v;
  else             out[idx] = v;
}

extern "C" void kernel_launch(void* const* d_in, const int* in_sizes, int n_in,
                              void* d_out, int out_size, void* d_ws, size_t ws_size,
                              hipStream_t stream) {
  const float* x = (const float*)d_in[0];   // fp32 [256,1152,8]
  const float* w = (const float*)d_in[1];   // fp32 [10,1152,16,8]
  float* out = (float*)d_out;               // fp32 [256,10,16]

  const size_t P = (size_t)BB * OO * DOUT;  // 40960 floats per plane
  float* s0 = (float*)d_ws;                 // 3 accumulator planes + V
  float* s1 = s0 + P;
  float* s2 = s1 + P;
  float* V  = s2 + P;

  hipMemsetAsync(s0, 0, 3 * P * sizeof(float), stream);  // zero the 3 planes

  const int pg = 1024;                      // 64 ic (fast) x 16 bg
  const int rg = (int)(P / 256);            // 160 blocks

  pass_kernel<0><<<pg, 256, 0, stream>>>(x, w, V, s0);
  reduce_kernel<0><<<rg, 256, 0, stream>>>(s0, V, out);
  pass_kernel<1><<<pg, 256, 0, stream>>>(x, w, V, s1);
  reduce_kernel<1><<<rg, 256, 0, stream>>>(s1, V, out);
  pass_kernel<2><<<pg, 256, 0, stream>>>(x, w, V, s2);
  reduce_kernel<2><<<rg, 256, 0, stream>>>(s2, V, out);
}